// Round 7
// baseline (497.505 us; speedup 1.0000x reference)
//
#include <hip/hip_runtime.h>
#include <hip/hip_bf16.h>

#define BATCH   4096
#define NIN     2048
#define NOUT    2048
#define GS      8

typedef __attribute__((ext_vector_type(8))) short  bf16x8;   // 8 bf16 = 4 VGPR (MFMA frag)
typedef __attribute__((ext_vector_type(4))) short  bf16x4;   // 8B
typedef __attribute__((ext_vector_type(4))) float  f32x4;

// round-to-nearest-even f32 -> bf16
__device__ __forceinline__ short f2bf(float f) {
    unsigned u = __builtin_bit_cast(unsigned, f);
    u += 0x7fffu + ((u >> 16) & 1u);
    return (short)(u >> 16);
}

__device__ __forceinline__ bf16x8 basis_bf16(float xv, const float* g) {
    const float KE = -7.2134752044448170f;   // -5 * log2(e)
    float e[GS], s = 0.f;
#pragma unroll
    for (int k = 0; k < GS; ++k) {
        float t = xv - g[k];
        e[k] = __builtin_amdgcn_exp2f(t * t * KE);
        s += e[k];
    }
    float rn = __builtin_amdgcn_rcpf(s + 1e-8f);
    bf16x8 fr;
#pragma unroll
    for (int k = 0; k < GS; ++k) fr[k] = f2bf(e[k] * rn);
    return fr;
}

// async 16B global -> LDS DMA (no VGPR round trip; LDS dest = wave base + lane*16)
__device__ __forceinline__ void async16(const void* g, void* l) {
    __builtin_amdgcn_global_load_lds(
        (const __attribute__((address_space(1))) unsigned*)g,
        (__attribute__((address_space(3))) unsigned*)l, 16, 0, 0);
}

// ======================= PASS 1: prep — cvt and basis CONCURRENT, 2:1 =======================
// cvt moves 335 MB (coef read + B_ws write), basis moves 166 MB + exp work ->
// 2048 cvt blocks vs 1024 basis blocks so both phases finish together.
#define PREP_BLOCKS 3072
#define CVT_BLOCKS  2048
#define TB 64
#define TI 32

__global__ __launch_bounds__(256, 4)
void kan_prep_kernel(const float* __restrict__ x, const float* __restrict__ coef,
                     const float* __restrict__ grid,
                     short* __restrict__ A_ws, short* __restrict__ B_ws)
{
    __shared__ float tile[TB][TI + 1];
    const int t = threadIdx.x;

    if (blockIdx.x < CVT_BLOCKS) {
        // ---- coef fp32 -> bf16: 8192 chunks of 4096 floats over 2048 blocks (4 each).
        // NT loads: coef is read-once -> don't evict A_ws/B_ws from L3.
        for (int c = blockIdx.x; c < (NIN * NOUT * GS) / 4096; c += CVT_BLOCKS) {
            const float* src = coef + (size_t)c * 4096;
            short*       dst = B_ws + (size_t)c * 4096;
            f32x4 v[4];
#pragma unroll
            for (int j = 0; j < 4; ++j)
                v[j] = __builtin_nontemporal_load((const f32x4*)(src + j * 1024 + t * 4));
#pragma unroll
            for (int j = 0; j < 4; ++j) {
                bf16x4 o;
#pragma unroll
                for (int k = 0; k < 4; ++k) o[k] = f2bf(v[j][k]);
                *(bf16x4*)(dst + j * 1024 + t * 4) = o;
            }
        }
        return;
    }

    // ---- basis: 4096 jobs of 64b x 32i tiles (LDS transpose) over 1024 blocks (4 each) ----
    float g[GS];
#pragma unroll
    for (int k = 0; k < GS; ++k) g[k] = grid[k];

    for (int job = blockIdx.x - CVT_BLOCKS; job < (NIN / TI) * (BATCH / TB);
         job += PREP_BLOCKS - CVT_BLOCKS) {
        const int i0 = (job & (NIN / TI - 1)) * TI;
        const int b0 = (job / (NIN / TI)) * TB;
        __syncthreads();                             // protect tile from previous job
#pragma unroll
        for (int p = 0; p < (TB * TI) / 256; ++p) {  // reads coalesced over i
            int idx = t + p * 256;
            int b_l = idx >> 5, i_l = idx & 31;
            tile[b_l][i_l] = x[(size_t)(b0 + b_l) * NIN + i0 + i_l];
        }
        __syncthreads();
#pragma unroll
        for (int it = 0; it < 8; ++it) {             // writes coalesced over b
            int b_l = (t & 31) + 32 * (it & 1);
            int i_l = (t >> 5) + 8 * (it >> 1);
            bf16x8 fr = basis_bf16(tile[b_l][i_l], g);
            *(bf16x8*)(A_ws + (size_t)(i0 + i_l) * (BATCH * GS)
                            + (size_t)(b0 + b_l) * GS) = fr;
        }
    }
}

// ============================ PASS 2: GEMM (split-K=2, atomic epilogue) ============================
// 128x128 tile, 4 waves (2x2 of 64x64). K-step = 8 i's (K=64), LDS DMA.
// 1024 blocks = 4 blocks/CU (reg-capped: 64 AGPR acc + ~60 VGPR = 4 waves/SIMD).
// out must be zeroed before launch; each element receives exactly 2 fp32 atomic adds.
__global__ __launch_bounds__(256, 4)
void kan_gemm_splitk(const short* __restrict__ A_ws, const short* __restrict__ B_ws,
                     float* __restrict__ out)
{
    __shared__ __align__(16) char As[16384];   // 8 i-slices x 128 rows x 16B
    __shared__ __align__(16) char Bs[16384];

    const int t    = threadIdx.x;
    const int wave = t >> 6;
    const int lane = t & 63;
    const int l15  = lane & 15;
    const int quad = lane >> 4;
    const int wm = wave & 1, wn = wave >> 1;
    const int m_blk = blockIdx.x * 128, n_blk = blockIdx.y * 128;
    const int z = blockIdx.z;

    f32x4 acc[4][4];
#pragma unroll
    for (int a = 0; a < 4; ++a)
#pragma unroll
        for (int b = 0; b < 4; ++b)
            acc[a][b] = (f32x4){0.f, 0.f, 0.f, 0.f};

    const char* Abase = (const char*)A_ws + (size_t)m_blk * (GS * 2);
    const char* Bbase = (const char*)B_ws + (size_t)n_blk * (GS * 2);
    const size_t strideA = (size_t)BATCH * GS * 2;   // 64 KB per i
    const size_t strideB = (size_t)NOUT  * GS * 2;   // 32 KB per i

    int dma_off[4], dma_iloc[4], dma_rem[4];
#pragma unroll
    for (int j = 0; j < 4; ++j) {
        dma_off[j]  = j * 4096 + t * 16;
        dma_iloc[j] = dma_off[j] >> 11;
        dma_rem[j]  = dma_off[j] & 2047;
    }

    const int i_lo = z * (NIN / 2), i_hi = i_lo + (NIN / 2);
    for (int i0 = i_lo; i0 < i_hi; i0 += 8) {
#pragma unroll
        for (int j = 0; j < 4; ++j) {
            const size_t i = (size_t)(i0 + dma_iloc[j]);
            async16(Abase + i * strideA + dma_rem[j], As + dma_off[j]);
            async16(Bbase + i * strideB + dma_rem[j], Bs + dma_off[j]);
        }
        __syncthreads();

#pragma unroll
        for (int s = 0; s < 2; ++s) {
            const int iloc = s * 4 + quad;
            bf16x8 af[4], bf[4];
#pragma unroll
            for (int ms = 0; ms < 4; ++ms)
                af[ms] = *(const bf16x8*)(As + (size_t)(iloc * 128 + wm * 64 + ms * 16 + l15) * 16);
#pragma unroll
            for (int ns = 0; ns < 4; ++ns)
                bf[ns] = *(const bf16x8*)(Bs + (size_t)(iloc * 128 + wn * 64 + ns * 16 + l15) * 16);
#pragma unroll
            for (int ms = 0; ms < 4; ++ms)
#pragma unroll
                for (int ns = 0; ns < 4; ++ns)
                    acc[ms][ns] = __builtin_amdgcn_mfma_f32_16x16x32_bf16(
                        af[ms], bf[ns], acc[ms][ns], 0, 0, 0);
        }
        __syncthreads();
    }

    // Atomic fp32 epilogue (device-scope HW atomic, no return). Each element is
    // hit by exactly z=0 and z=1 -> negligible contention, fp32 accumulation.
    const int m_base = m_blk + wm * 64;
    const int n_base = n_blk + wn * 64;
#pragma unroll
    for (int ms = 0; ms < 4; ++ms)
#pragma unroll
        for (int ns = 0; ns < 4; ++ns) {
            const int col = n_base + ns * 16 + l15;
#pragma unroll
            for (int r = 0; r < 4; ++r) {
                const int row = m_base + ms * 16 + quad * 4 + r;
                unsafeAtomicAdd(&out[(size_t)row * NOUT + col], acc[ms][ns][r]);
            }
        }
}

// ==================== fallback: fused (no workspace) ====================
__global__ __launch_bounds__(256, 2)
void kan_fused_kernel(const float* __restrict__ x, const float* __restrict__ coef,
                      const float* __restrict__ grid, float* __restrict__ out)
{
    const int tid  = threadIdx.x;
    const int wave = tid >> 6;
    const int lane = tid & 63;
    const int l15  = lane & 15;
    const int quad = lane >> 4;
    const int m_base = blockIdx.x * 128 + (wave & 1) * 64;
    const int n_base = blockIdx.y * 128 + (wave >> 1) * 64;

    float g[GS];
#pragma unroll
    for (int k = 0; k < GS; ++k) g[k] = grid[k];

    f32x4 acc[4][4];
#pragma unroll
    for (int a = 0; a < 4; ++a)
#pragma unroll
        for (int b = 0; b < 4; ++b) acc[a][b] = (f32x4){0.f, 0.f, 0.f, 0.f};

    const float* xp = x + (size_t)(m_base + l15) * NIN + quad;
    const float* cp = coef + (size_t)quad * (NOUT * GS) + (size_t)(n_base + l15) * GS;

    for (int i0 = 0; i0 < NIN; i0 += 4) {
        f32x4 braw[4][2];
#pragma unroll
        for (int ns = 0; ns < 4; ++ns) {
            const float* p = cp + ns * (16 * GS);
            braw[ns][0] = *(const f32x4*)(p);
            braw[ns][1] = *(const f32x4*)(p + 4);
        }
        bf16x8 afrag[4];
#pragma unroll
        for (int ms = 0; ms < 4; ++ms)
            afrag[ms] = basis_bf16(xp[ms * 16 * NIN], g);
        bf16x8 bfrag[4];
#pragma unroll
        for (int ns = 0; ns < 4; ++ns) {
            bf16x8 fr;
#pragma unroll
            for (int k = 0; k < 4; ++k) { fr[k] = f2bf(braw[ns][0][k]); fr[k+4] = f2bf(braw[ns][1][k]); }
            bfrag[ns] = fr;
        }
#pragma unroll
        for (int ms = 0; ms < 4; ++ms)
#pragma unroll
            for (int ns = 0; ns < 4; ++ns)
                acc[ms][ns] = __builtin_amdgcn_mfma_f32_16x16x32_bf16(
                    afrag[ms], bfrag[ns], acc[ms][ns], 0, 0, 0);
        xp += 4;
        cp += 4 * (NOUT * GS);
    }
#pragma unroll
    for (int ms = 0; ms < 4; ++ms)
#pragma unroll
        for (int ns = 0; ns < 4; ++ns) {
            const int col = n_base + ns * 16 + l15;
#pragma unroll
            for (int r = 0; r < 4; ++r)
                out[(size_t)(m_base + ms * 16 + quad * 4 + r) * NOUT + col] = acc[ms][ns][r];
        }
}

extern "C" void kernel_launch(void* const* d_in, const int* in_sizes, int n_in,
                              void* d_out, int out_size, void* d_ws, size_t ws_size,
                              hipStream_t stream) {
    const float* x    = (const float*)d_in[0];
    const float* coef = (const float*)d_in[1];
    const float* grid = (const float*)d_in[2];
    float* out        = (float*)d_out;

    const size_t a_elems = (size_t)NIN * BATCH * GS;         // 67.1M shorts = 134 MB
    const size_t b_elems = (size_t)NIN * NOUT * GS;          // 33.5M shorts =  67 MB
    const size_t need    = (a_elems + b_elems) * sizeof(short);

    if (ws_size >= need) {
        short* A_ws = (short*)d_ws;
        short* B_ws = A_ws + a_elems;

        // zero out (atomic epilogue accumulates into it); stream-ordered, capturable
        hipMemsetAsync(out, 0, (size_t)out_size * sizeof(float), stream);

        kan_prep_kernel<<<PREP_BLOCKS, 256, 0, stream>>>(x, coef, grid, A_ws, B_ws);

        dim3 g2(BATCH / 128, NOUT / 128, 2);                 // 1024 blocks = 4/CU
        kan_gemm_splitk<<<g2, 256, 0, stream>>>(A_ws, B_ws, out);
    } else {
        dim3 grd(BATCH / 128, NOUT / 128);
        kan_fused_kernel<<<grd, 256, 0, stream>>>(x, coef, grid, out);
    }
}